// Round 6
// baseline (316.337 us; speedup 1.0000x reference)
//
#include <hip/hip_runtime.h>
#include <hip/hip_bf16.h>

#define N_ROWS 8192
#define DIM    1024
#define NCLS   10240
#define S_SCALE 30.0f
#define M_LARGE 0.4f
#define M_SMALL 0.1f

typedef __attribute__((ext_vector_type(8))) short bf16x8;
typedef __attribute__((ext_vector_type(16))) float f32x16;

__device__ __forceinline__ unsigned short f2bf(float f){
    unsigned int u = __builtin_bit_cast(unsigned int, f);
    unsigned int r = (u + 0x7fffu + ((u >> 16) & 1u)) >> 16;
    return (unsigned short)r;
}

#define GLD16(gp, lp) __builtin_amdgcn_global_load_lds( \
    (const __attribute__((address_space(1))) unsigned int*)(gp), \
    (__attribute__((address_space(3))) unsigned int*)(lp), 16, 0, 0)

// ---------------- prep: inv L2 norms + raw f32->bf16 conversion, zero gsum ----------------
__global__ void prep_kernel(const float* __restrict__ x, const float* __restrict__ w,
                            float* __restrict__ inv_x, float* __restrict__ inv_w,
                            float* __restrict__ gsum,
                            unsigned short* __restrict__ xb, unsigned short* __restrict__ wb){
    int b = blockIdx.x;
    bool isx = (b < N_ROWS);
    int r = isx ? b : b - N_ROWS;
    const float4* src = (const float4*)((isx ? x : w) + (size_t)r * DIM);
    float4 v = src[threadIdx.x];                      // 256 threads * 4 = 1024
    ushort4 pk;
    pk.x = f2bf(v.x); pk.y = f2bf(v.y); pk.z = f2bf(v.z); pk.w = f2bf(v.w);
    ushort4* dst = (ushort4*)((isx ? xb : wb) + (size_t)r * DIM);
    dst[threadIdx.x] = pk;
    float ss = v.x*v.x + v.y*v.y + v.z*v.z + v.w*v.w;
    #pragma unroll
    for (int o = 32; o; o >>= 1) ss += __shfl_down(ss, o);
    __shared__ float part[4];
    int lane = threadIdx.x & 63, wid = threadIdx.x >> 6;
    if (lane == 0) part[wid] = ss;
    __syncthreads();
    if (threadIdx.x == 0){
        float t = part[0] + part[1] + part[2] + part[3];
        float inv = 1.0f / fmaxf(sqrtf(t), 1e-12f);
        if (isx){ inv_x[r] = inv; gsum[r] = 0.0f; }
        else      inv_w[r] = inv;
    }
}

// ---------------- target logit: exact f32 dot x_i . w_label ----------------
__global__ void target_kernel(const float* __restrict__ x, const float* __restrict__ w,
                              const int* __restrict__ labels,
                              const float* __restrict__ inv_x, const float* __restrict__ inv_w,
                              float* __restrict__ tgt){
    int wid = threadIdx.x >> 6, lane = threadIdx.x & 63;
    int i = blockIdx.x * 4 + wid;
    int lab = labels[i];
    const float4* xp = (const float4*)(x + (size_t)i   * DIM);
    const float4* wp = (const float4*)(w + (size_t)lab * DIM);
    float acc = 0.f;
    #pragma unroll
    for (int c = 0; c < 4; ++c){
        float4 a = xp[c*64 + lane];
        float4 b = wp[c*64 + lane];
        acc += a.x*b.x + a.y*b.y + a.z*b.z + a.w*b.w;
    }
    #pragma unroll
    for (int o = 32; o; o >>= 1) acc += __shfl_down(acc, o);
    if (lane == 0){
        float c = acc * inv_x[i] * inv_w[lab];
        c = fminf(fmaxf(c, -1.f), 1.f);
        tgt[i] = c;
    }
}

// ---------------- fused bf16 GEMM (256x256 tile, 4-phase, 32x32x16 MFMA) ----------------
#define BM 256
#define BN 256
#define BK 64
#define NTILE (DIM/BK)       // 16
#define GRID_X (NCLS/BN)     // 40
#define GRID_Y (N_ROWS/BM)   // 32
#define NWG (GRID_X*GRID_Y)  // 1280, % 8 == 0

// read one A-frag pair (k-steps KB..KB+1) for m-block MM into dst[2]
#define LDA(dst, MM, KB) { \
    int r_ = wm*128 + (MM)*32 + l32; \
    int sw_ = r_ & 7; \
    dst[0] = *(const bf16x8*)&As[b][r_*BK + ((((KB)+h)     ^ sw_) << 3)]; \
    dst[1] = *(const bf16x8*)&As[b][r_*BK + ((((KB)+2+h)   ^ sw_) << 3)]; }
#define LDB(dst, NN, KB) { \
    int r_ = wn*64 + (NN)*32 + l32; \
    int sw_ = r_ & 7; \
    dst[0] = *(const bf16x8*)&Bs[b][r_*BK + ((((KB)+h)     ^ sw_) << 3)]; \
    dst[1] = *(const bf16x8*)&Bs[b][r_*BK + ((((KB)+2+h)   ^ sw_) << 3)]; }

#define MFMA8(M0, M1) \
    acc[M0][0] = __builtin_amdgcn_mfma_f32_32x32x16_bf16(af0[0], bf0[0], acc[M0][0], 0, 0, 0); \
    acc[M0][1] = __builtin_amdgcn_mfma_f32_32x32x16_bf16(af0[0], bf1[0], acc[M0][1], 0, 0, 0); \
    acc[M1][0] = __builtin_amdgcn_mfma_f32_32x32x16_bf16(af1[0], bf0[0], acc[M1][0], 0, 0, 0); \
    acc[M1][1] = __builtin_amdgcn_mfma_f32_32x32x16_bf16(af1[0], bf1[0], acc[M1][1], 0, 0, 0); \
    acc[M0][0] = __builtin_amdgcn_mfma_f32_32x32x16_bf16(af0[1], bf0[1], acc[M0][0], 0, 0, 0); \
    acc[M0][1] = __builtin_amdgcn_mfma_f32_32x32x16_bf16(af0[1], bf1[1], acc[M0][1], 0, 0, 0); \
    acc[M1][0] = __builtin_amdgcn_mfma_f32_32x32x16_bf16(af1[1], bf0[1], acc[M1][0], 0, 0, 0); \
    acc[M1][1] = __builtin_amdgcn_mfma_f32_32x32x16_bf16(af1[1], bf1[1], acc[M1][1], 0, 0, 0);

#define PHASE_SYNC_PRE \
    __builtin_amdgcn_s_barrier(); \
    asm volatile("s_waitcnt lgkmcnt(0)" ::: "memory"); \
    __builtin_amdgcn_sched_barrier(0); \
    __builtin_amdgcn_s_setprio(1);
#define PHASE_SYNC_POST \
    __builtin_amdgcn_s_setprio(0); \
    __builtin_amdgcn_s_barrier();

__global__ __launch_bounds__(512, 2) void gemm_kernel(
        const unsigned short* __restrict__ xb, const unsigned short* __restrict__ wb,
        const float* __restrict__ inv_x, const float* __restrict__ inv_w,
        float* __restrict__ gsum){
    __shared__ __align__(16) unsigned short As[2][BM*BK];   // 2 x 32 KB
    __shared__ __align__(16) unsigned short Bs[2][BN*BK];   // 2 x 32 KB
    __shared__ float sumrow[BM];

    int tid = threadIdx.x;
    int bid = blockIdx.x;
    // bijective XCD swizzle
    int swz = (bid & 7) * (NWG/8) + (bid >> 3);
    int by = swz / GRID_X, bx = swz % GRID_X;
    int row0 = by * BM, col0 = bx * BN;
    int wid = tid >> 6, lane = tid & 63;
    int wm = wid >> 2, wn = wid & 3;           // 2M x 4N wave grid; wave owns 128x64
    int l32 = lane & 31, h = lane >> 5;

    if (tid < BM) sumrow[tid] = 0.f;

    // staging geometry: one GLD16 instr = 512 thr x 16B = 64 rows x 64 cols
    int srow = tid >> 3;                       // 0..63
    int csrc = (tid & 7) ^ (srow & 7);         // pre-swizzled source chunk
    const unsigned short* gA = xb + (size_t)(row0 + srow) * DIM + csrc * 8;
    const unsigned short* gB = wb + (size_t)(col0 + srow) * DIM + csrc * 8;
    int ldso = srow * BK + (tid & 7) * 8;      // linear LDS dest (elements)

    f32x16 acc[4][2] = {};

    // prologue: stage tile 0 fully
    #pragma unroll
    for (int hh = 0; hh < 4; ++hh){
        GLD16(gA + (size_t)(hh*64)*DIM, &As[0][hh*64*BK + ldso]);
        GLD16(gB + (size_t)(hh*64)*DIM, &Bs[0][hh*64*BK + ldso]);
    }
    asm volatile("s_waitcnt vmcnt(0)" ::: "memory");
    __builtin_amdgcn_s_barrier();

    for (int kt = 0; kt < NTILE; ++kt){
        int b = kt & 1, nb = b ^ 1;

        // issue ALL next-tile stages up front: by the boundary drain they are
        // ~4 phases (~3000 cycles) old, so vmcnt(0) there is nearly free.
        // Safe: buffer nb was last read in tile kt-1, whose boundary barrier
        // precedes these issues in program order.
        if (kt + 1 < NTILE){
            int knext = (kt + 1) * BK;
            GLD16(gA + knext,                    &As[nb][ldso]);
            GLD16(gA + knext + (size_t)64*DIM,   &As[nb][64*BK + ldso]);
            GLD16(gA + knext + (size_t)128*DIM,  &As[nb][128*BK + ldso]);
            GLD16(gA + knext + (size_t)192*DIM,  &As[nb][192*BK + ldso]);
            GLD16(gB + knext,                    &Bs[nb][ldso]);
            GLD16(gB + knext + (size_t)64*DIM,   &Bs[nb][64*BK + ldso]);
            GLD16(gB + knext + (size_t)128*DIM,  &Bs[nb][128*BK + ldso]);
            GLD16(gB + knext + (size_t)192*DIM,  &Bs[nb][192*BK + ldso]);
        }

        bf16x8 af0[2], af1[2], bf0[2], bf1[2];

        // ---- P0: m0-1, k-steps 0-1 (+ B load)
        LDA(af0, 0, 0); LDA(af1, 1, 0); LDB(bf0, 0, 0); LDB(bf1, 1, 0);
        PHASE_SYNC_PRE
        MFMA8(0, 1)
        PHASE_SYNC_POST

        // ---- P1: m2-3, k-steps 0-1 (reuse B regs)
        LDA(af0, 2, 0); LDA(af1, 3, 0);
        PHASE_SYNC_PRE
        MFMA8(2, 3)
        PHASE_SYNC_POST

        // ---- P2: m0-1, k-steps 2-3 (+ B load)
        LDA(af0, 0, 4); LDA(af1, 1, 4); LDB(bf0, 0, 4); LDB(bf1, 1, 4);
        PHASE_SYNC_PRE
        MFMA8(0, 1)
        PHASE_SYNC_POST

        // ---- P3: m2-3, k-steps 2-3
        LDA(af0, 2, 4); LDA(af1, 3, 4);
        PHASE_SYNC_PRE
        MFMA8(2, 3)
        __builtin_amdgcn_s_setprio(0);

        // ---- K-tile boundary: next tile's stages are ~4 phases old
        asm volatile("s_waitcnt vmcnt(0)" ::: "memory");
        __builtin_amdgcn_sched_barrier(0);
        __builtin_amdgcn_s_barrier();
    }

    // epilogue: scale by inv_x[i]*inv_w[j], clamp, exp(S*.), row-sum
    // 32x32 C/D layout: col = lane&31, row = (q&3) + 8*(q>>2) + 4*h
    float iw0 = inv_w[col0 + wn*64 + l32];
    float iw1 = inv_w[col0 + wn*64 + 32 + l32];
    #pragma unroll
    for (int m = 0; m < 4; ++m){
        #pragma unroll
        for (int q = 0; q < 16; ++q){
            int rl = wm*128 + m*32 + (q & 3) + 8*(q >> 2) + 4*h;
            float ix = inv_x[row0 + rl];
            float c0 = acc[m][0][q] * ix * iw0;
            float c1 = acc[m][1][q] * ix * iw1;
            c0 = fminf(fmaxf(c0, -1.f), 1.f);
            c1 = fminf(fmaxf(c1, -1.f), 1.f);
            float v = __expf(S_SCALE * c0) + __expf(S_SCALE * c1);
            v += __shfl_xor(v, 1);
            v += __shfl_xor(v, 2);
            v += __shfl_xor(v, 4);
            v += __shfl_xor(v, 8);
            v += __shfl_xor(v, 16);
            if (l32 == 0) atomicAdd(&sumrow[rl], v);
        }
    }
    __syncthreads();
    if (tid < BM) atomicAdd(&gsum[row0 + tid], sumrow[tid]);
}

// ---------------- finalize: per-row loss, mean ----------------
__global__ void finalize_kernel(const float* __restrict__ tgt, const float* __restrict__ gsum,
                                const int* __restrict__ labels, float* __restrict__ out){
    double local = 0.0;
    for (int i = threadIdx.x; i < N_ROWS; i += 256){
        float tv = tgt[i];
        float m  = (labels[i] <= 5) ? M_LARGE : M_SMALL;
        float numer = S_SCALE * (tv - m);
        float excl  = gsum[i] - __expf(S_SCALE * tv);
        float denom = __expf(numer) + excl;
        float L = numer - logf(denom);
        local += (double)L;
    }
    #pragma unroll
    for (int o = 32; o; o >>= 1) local += __shfl_down(local, o);
    __shared__ double part[4];
    int lane = threadIdx.x & 63, wid = threadIdx.x >> 6;
    if (lane == 0) part[wid] = local;
    __syncthreads();
    if (threadIdx.x == 0){
        double s = part[0] + part[1] + part[2] + part[3];
        out[0] = (float)(-s / (double)N_ROWS);
    }
}

extern "C" void kernel_launch(void* const* d_in, const int* in_sizes, int n_in,
                              void* d_out, int out_size, void* d_ws, size_t ws_size,
                              hipStream_t stream) {
    const float* x      = (const float*)d_in[0];
    const int*   labels = (const int*)  d_in[1];
    const float* w      = (const float*)d_in[2];

    float* ws    = (float*)d_ws;
    float* inv_x = ws;                    // N
    float* inv_w = inv_x + N_ROWS;        // C
    float* tgt   = inv_w + NCLS;          // N
    float* gsum  = tgt   + N_ROWS;        // N
    unsigned short* xb = (unsigned short*)(gsum + N_ROWS);  // N*D bf16
    unsigned short* wb = xb + (size_t)N_ROWS * DIM;         // C*D bf16

    prep_kernel<<<N_ROWS + NCLS, 256, 0, stream>>>(x, w, inv_x, inv_w, gsum, xb, wb);
    target_kernel<<<N_ROWS/4, 256, 0, stream>>>(x, w, labels, inv_x, inv_w, tgt);
    gemm_kernel<<<NWG, 512, 0, stream>>>(xb, wb, inv_x, inv_w, gsum);
    finalize_kernel<<<1, 256, 0, stream>>>(tgt, gsum, labels, (float*)d_out);
}

// Round 7
// 264.392 us; speedup vs baseline: 1.1965x; 1.1965x over previous
//
#include <hip/hip_runtime.h>
#include <hip/hip_bf16.h>

#define N_ROWS 8192
#define DIM    1024
#define NCLS   10240
#define S_SCALE 30.0f
#define M_LARGE 0.4f
#define M_SMALL 0.1f

typedef __attribute__((ext_vector_type(8))) short bf16x8;
typedef __attribute__((ext_vector_type(4))) float f32x4;

__device__ __forceinline__ unsigned short f2bf(float f){
    unsigned int u = __builtin_bit_cast(unsigned int, f);
    unsigned int r = (u + 0x7fffu + ((u >> 16) & 1u)) >> 16;
    return (unsigned short)r;
}

#define GLD16(gp, lp) __builtin_amdgcn_global_load_lds( \
    (const __attribute__((address_space(1))) unsigned int*)(gp), \
    (__attribute__((address_space(3))) unsigned int*)(lp), 16, 0, 0)

// ---------------- prep: inv L2 norms + raw f32->bf16 conversion, zero gsum ----------------
__global__ void prep_kernel(const float* __restrict__ x, const float* __restrict__ w,
                            float* __restrict__ inv_x, float* __restrict__ inv_w,
                            float* __restrict__ gsum,
                            unsigned short* __restrict__ xb, unsigned short* __restrict__ wb){
    int b = blockIdx.x;
    bool isx = (b < N_ROWS);
    int r = isx ? b : b - N_ROWS;
    const float4* src = (const float4*)((isx ? x : w) + (size_t)r * DIM);
    float4 v = src[threadIdx.x];                      // 256 threads * 4 = 1024
    ushort4 pk;
    pk.x = f2bf(v.x); pk.y = f2bf(v.y); pk.z = f2bf(v.z); pk.w = f2bf(v.w);
    ushort4* dst = (ushort4*)((isx ? xb : wb) + (size_t)r * DIM);
    dst[threadIdx.x] = pk;
    float ss = v.x*v.x + v.y*v.y + v.z*v.z + v.w*v.w;
    #pragma unroll
    for (int o = 32; o; o >>= 1) ss += __shfl_down(ss, o);
    __shared__ float part[4];
    int lane = threadIdx.x & 63, wid = threadIdx.x >> 6;
    if (lane == 0) part[wid] = ss;
    __syncthreads();
    if (threadIdx.x == 0){
        float t = part[0] + part[1] + part[2] + part[3];
        float inv = 1.0f / fmaxf(sqrtf(t), 1e-12f);
        if (isx){ inv_x[r] = inv; gsum[r] = 0.0f; }
        else      inv_w[r] = inv;
    }
}

// ---------------- target logit: exact f32 dot x_i . w_label ----------------
__global__ void target_kernel(const float* __restrict__ x, const float* __restrict__ w,
                              const int* __restrict__ labels,
                              const float* __restrict__ inv_x, const float* __restrict__ inv_w,
                              float* __restrict__ tgt){
    int wid = threadIdx.x >> 6, lane = threadIdx.x & 63;
    int i = blockIdx.x * 4 + wid;
    int lab = labels[i];
    const float4* xp = (const float4*)(x + (size_t)i   * DIM);
    const float4* wp = (const float4*)(w + (size_t)lab * DIM);
    float acc = 0.f;
    #pragma unroll
    for (int c = 0; c < 4; ++c){
        float4 a = xp[c*64 + lane];
        float4 b = wp[c*64 + lane];
        acc += a.x*b.x + a.y*b.y + a.z*b.z + a.w*b.w;
    }
    #pragma unroll
    for (int o = 32; o; o >>= 1) acc += __shfl_down(acc, o);
    if (lane == 0){
        float c = acc * inv_x[i] * inv_w[lab];
        c = fminf(fmaxf(c, -1.f), 1.f);
        tgt[i] = c;
    }
}

// ---------------- fused bf16 GEMM (256x256 tile, 4-phase/K-tile, 16x16x32 MFMA) ----------------
#define BM 256
#define BN 256
#define BK 64
#define NTILE (DIM/BK)       // 16
#define GRID_X (NCLS/BN)     // 40
#define GRID_Y (N_ROWS/BM)   // 32
#define NWG (GRID_X*GRID_Y)  // 1280, % 8 == 0

__global__ __launch_bounds__(512, 2) void gemm_kernel(
        const unsigned short* __restrict__ xb, const unsigned short* __restrict__ wb,
        const float* __restrict__ inv_x, const float* __restrict__ inv_w,
        float* __restrict__ gsum){
    __shared__ __align__(16) unsigned short As[2][BM*BK];   // 2 x 32 KB
    __shared__ __align__(16) unsigned short Bs[2][BN*BK];   // 2 x 32 KB
    __shared__ float sumrow[BM];

    int tid = threadIdx.x;
    int bid = blockIdx.x;
    // bijective XCD swizzle
    int swz = (bid & 7) * (NWG/8) + (bid >> 3);
    int by = swz / GRID_X, bx = swz % GRID_X;
    int row0 = by * BM, col0 = bx * BN;
    int wid = tid >> 6, lane = tid & 63;
    int wm = wid >> 2, wn = wid & 3;           // 2M x 4N wave grid; wave owns 128x64
    int g = lane >> 4, l16 = lane & 15;

    if (tid < BM) sumrow[tid] = 0.f;

    // staging geometry: one GLD16 instr = 512 thr x 16B = 64 rows x 64 cols
    int srow = tid >> 3;                       // 0..63
    int csrc = (tid & 7) ^ (srow & 7);         // pre-swizzled source chunk
    const unsigned short* gA = xb + (size_t)(row0 + srow) * DIM + csrc * 8;
    const unsigned short* gB = wb + (size_t)(col0 + srow) * DIM + csrc * 8;
    int ldso = srow * BK + (tid & 7) * 8;      // linear LDS dest (elements)

    f32x4 acc[8][4] = {};

    // prologue: stage tile 0 fully
    #pragma unroll
    for (int h = 0; h < 4; ++h){
        GLD16(gA + (size_t)(h*64)*DIM, &As[0][h*64*BK + ldso]);
        GLD16(gB + (size_t)(h*64)*DIM, &Bs[0][h*64*BK + ldso]);
    }
    asm volatile("s_waitcnt vmcnt(0)" ::: "memory");
    __builtin_amdgcn_s_barrier();

    for (int kt = 0; kt < NTILE; ++kt){
        int b = kt & 1, nb = b ^ 1;

        // issue ALL next-tile stages up front: by the boundary drain they are
        // ~4 phases (~2-3k cycles) old, so vmcnt(0) there is nearly free.
        // Safe: buffer nb was last read in tile kt-1, whose boundary barrier
        // precedes these issues in program order.
        if (kt + 1 < NTILE){
            int knext = (kt + 1) * BK;
            GLD16(gA + knext,                    &As[nb][ldso]);
            GLD16(gA + knext + (size_t)64*DIM,   &As[nb][64*BK + ldso]);
            GLD16(gA + knext + (size_t)128*DIM,  &As[nb][128*BK + ldso]);
            GLD16(gA + knext + (size_t)192*DIM,  &As[nb][192*BK + ldso]);
            GLD16(gB + knext,                    &Bs[nb][ldso]);
            GLD16(gB + knext + (size_t)64*DIM,   &Bs[nb][64*BK + ldso]);
            GLD16(gB + knext + (size_t)128*DIM,  &Bs[nb][128*BK + ldso]);
            GLD16(gB + knext + (size_t)192*DIM,  &Bs[nb][192*BK + ldso]);
        }

        bf16x8 af[4], bfv[4];

        // ---- P0: read A m0-3 k0 + B n0-3 k0
        #pragma unroll
        for (int m = 0; m < 4; ++m){
            int r = wm*128 + m*16 + l16;
            af[m] = *(const bf16x8*)&As[b][r*BK + ((g ^ (r & 7)) << 3)];
        }
        #pragma unroll
        for (int n = 0; n < 4; ++n){
            int r = wn*64 + n*16 + l16;
            bfv[n] = *(const bf16x8*)&Bs[b][r*BK + ((g ^ (r & 7)) << 3)];
        }
        __builtin_amdgcn_s_barrier();
        asm volatile("s_waitcnt lgkmcnt(0)" ::: "memory");
        __builtin_amdgcn_sched_barrier(0);
        __builtin_amdgcn_s_setprio(1);
        #pragma unroll
        for (int m = 0; m < 4; ++m)
            #pragma unroll
            for (int n = 0; n < 4; ++n)
                acc[m][n] = __builtin_amdgcn_mfma_f32_16x16x32_bf16(af[m], bfv[n], acc[m][n], 0, 0, 0);
        __builtin_amdgcn_s_setprio(0);
        __builtin_amdgcn_s_barrier();

        // ---- P1: read A m4-7 k0 ; reuse B k0 regs
        #pragma unroll
        for (int m = 0; m < 4; ++m){
            int r = wm*128 + (m+4)*16 + l16;
            af[m] = *(const bf16x8*)&As[b][r*BK + ((g ^ (r & 7)) << 3)];
        }
        __builtin_amdgcn_s_barrier();
        asm volatile("s_waitcnt lgkmcnt(0)" ::: "memory");
        __builtin_amdgcn_sched_barrier(0);
        __builtin_amdgcn_s_setprio(1);
        #pragma unroll
        for (int m = 0; m < 4; ++m)
            #pragma unroll
            for (int n = 0; n < 4; ++n)
                acc[m+4][n] = __builtin_amdgcn_mfma_f32_16x16x32_bf16(af[m], bfv[n], acc[m+4][n], 0, 0, 0);
        __builtin_amdgcn_s_setprio(0);
        __builtin_amdgcn_s_barrier();

        // ---- P2: read A m0-3 k1 + B n0-3 k1
        #pragma unroll
        for (int m = 0; m < 4; ++m){
            int r = wm*128 + m*16 + l16;
            af[m] = *(const bf16x8*)&As[b][r*BK + (((4+g) ^ (r & 7)) << 3)];
        }
        #pragma unroll
        for (int n = 0; n < 4; ++n){
            int r = wn*64 + n*16 + l16;
            bfv[n] = *(const bf16x8*)&Bs[b][r*BK + (((4+g) ^ (r & 7)) << 3)];
        }
        __builtin_amdgcn_s_barrier();
        asm volatile("s_waitcnt lgkmcnt(0)" ::: "memory");
        __builtin_amdgcn_sched_barrier(0);
        __builtin_amdgcn_s_setprio(1);
        #pragma unroll
        for (int m = 0; m < 4; ++m)
            #pragma unroll
            for (int n = 0; n < 4; ++n)
                acc[m][n] = __builtin_amdgcn_mfma_f32_16x16x32_bf16(af[m], bfv[n], acc[m][n], 0, 0, 0);
        __builtin_amdgcn_s_setprio(0);
        __builtin_amdgcn_s_barrier();

        // ---- P3: read A m4-7 k1
        #pragma unroll
        for (int m = 0; m < 4; ++m){
            int r = wm*128 + (m+4)*16 + l16;
            af[m] = *(const bf16x8*)&As[b][r*BK + (((4+g) ^ (r & 7)) << 3)];
        }
        __builtin_amdgcn_s_barrier();
        asm volatile("s_waitcnt lgkmcnt(0)" ::: "memory");
        __builtin_amdgcn_sched_barrier(0);
        __builtin_amdgcn_s_setprio(1);
        #pragma unroll
        for (int m = 0; m < 4; ++m)
            #pragma unroll
            for (int n = 0; n < 4; ++n)
                acc[m+4][n] = __builtin_amdgcn_mfma_f32_16x16x32_bf16(af[m], bfv[n], acc[m+4][n], 0, 0, 0);
        __builtin_amdgcn_s_setprio(0);

        // ---- K-tile boundary: next tile's stages are ~4 phases old
        asm volatile("s_waitcnt vmcnt(0)" ::: "memory");
        __builtin_amdgcn_sched_barrier(0);
        __builtin_amdgcn_s_barrier();
    }

    // epilogue: scale by inv_x[i]*inv_w[j], clamp, exp(S*.), row-sum
    float iw[4];
    #pragma unroll
    for (int n = 0; n < 4; ++n) iw[n] = inv_w[col0 + wn*64 + n*16 + l16];
    #pragma unroll
    for (int m = 0; m < 8; ++m){
        #pragma unroll
        for (int rg = 0; rg < 4; ++rg){
            int rl = wm*128 + m*16 + g*4 + rg;       // local row of this value
            float ix = inv_x[row0 + rl];
            float v = 0.f;
            #pragma unroll
            for (int n = 0; n < 4; ++n){
                float c = acc[m][n][rg] * ix * iw[n];
                c = fminf(fmaxf(c, -1.f), 1.f);
                v += __expf(S_SCALE * c);
            }
            v += __shfl_xor(v, 1);
            v += __shfl_xor(v, 2);
            v += __shfl_xor(v, 4);
            v += __shfl_xor(v, 8);
            if (l16 == 0) atomicAdd(&sumrow[rl], v);
        }
    }
    __syncthreads();
    if (tid < BM) atomicAdd(&gsum[row0 + tid], sumrow[tid]);
}

// ---------------- finalize: per-row loss, mean ----------------
__global__ void finalize_kernel(const float* __restrict__ tgt, const float* __restrict__ gsum,
                                const int* __restrict__ labels, float* __restrict__ out){
    double local = 0.0;
    for (int i = threadIdx.x; i < N_ROWS; i += 256){
        float tv = tgt[i];
        float m  = (labels[i] <= 5) ? M_LARGE : M_SMALL;
        float numer = S_SCALE * (tv - m);
        float excl  = gsum[i] - __expf(S_SCALE * tv);
        float denom = __expf(numer) + excl;
        float L = numer - logf(denom);
        local += (double)L;
    }
    #pragma unroll
    for (int o = 32; o; o >>= 1) local += __shfl_down(local, o);
    __shared__ double part[4];
    int lane = threadIdx.x & 63, wid = threadIdx.x >> 6;
    if (lane == 0) part[wid] = local;
    __syncthreads();
    if (threadIdx.x == 0){
        double s = part[0] + part[1] + part[2] + part[3];
        out[0] = (float)(-s / (double)N_ROWS);
    }
}

extern "C" void kernel_launch(void* const* d_in, const int* in_sizes, int n_in,
                              void* d_out, int out_size, void* d_ws, size_t ws_size,
                              hipStream_t stream) {
    const float* x      = (const float*)d_in[0];
    const int*   labels = (const int*)  d_in[1];
    const float* w      = (const float*)d_in[2];

    float* ws    = (float*)d_ws;
    float* inv_x = ws;                    // N
    float* inv_w = inv_x + N_ROWS;        // C
    float* tgt   = inv_w + NCLS;          // N
    float* gsum  = tgt   + N_ROWS;        // N
    unsigned short* xb = (unsigned short*)(gsum + N_ROWS);  // N*D bf16
    unsigned short* wb = xb + (size_t)N_ROWS * DIM;         // C*D bf16

    prep_kernel<<<N_ROWS + NCLS, 256, 0, stream>>>(x, w, inv_x, inv_w, gsum, xb, wb);
    target_kernel<<<N_ROWS/4, 256, 0, stream>>>(x, w, labels, inv_x, inv_w, tgt);
    gemm_kernel<<<NWG, 512, 0, stream>>>(xb, wb, inv_x, inv_w, gsum);
    finalize_kernel<<<1, 256, 0, stream>>>(tgt, gsum, labels, (float*)d_out);
}